// Round 9
// baseline (2998.935 us; speedup 1.0000x reference)
//
#include <hip/hip_runtime.h>
#include <hip/hip_bf16.h>

// ---------------------------------------------------------------------------
// LSTM_66675072303478: 2-layer LSTM (B=512,S=128,E=7,H=1024) + FC(1024->672)
//
// v20 = v19 (2828us best) with the two SERIAL floops merged into CONCURRENT
// halves of a 1024-thread block (16 waves/CU, was 8):
//  - Ledger: LDS-BW cut (v17) neutral, vmcnt-drain removal (v16/17) neutral,
//    split-flags (v19) +3%. MfmaUtil 25 + VALUBusy 22, Occupancy 24% (2
//    waves/SIMD) -> binder is per-iteration LATENCY chains that 2 lockstep
//    waves/SIMD can't hide.
//  - Fix: half0 (waves 0-7) runs v15's floop1 <D0,D1> (L0 + Wi1-half on
//    h_a) while half1 (waves 8-15) runs floop2 <false,D1> (Wh1-half on h_b)
//    AT THE SAME TIME, sharing the same 17 workgroup barriers (identical
//    count in both template instantiations; s_barrier counts arrivals, so
//    divergent-but-matching barriers are legal). Each SIMD: 2+2 waves at
//    different chain points -> stalls overlap. Loop wall ~ max not sum;
//    barrier count per round 34 -> 17.
//  - half1 exports acc1 partials via the retired B0lds buffer (32KB, free
//    after the final common barrier); half0 merges (+= ) and runs both
//    proven epilogues unchanged. Both flag waits move to round start.
//  - LDS: 80KB (half0: A+B0+B1) + 48KB (half1: A2+B1b) + 7KB misc = 135KB.
//  - Everything else v15/v19-verbatim: floop template, XOR swizzle
//    (0 conflicts), gate-interleaved epilogues, EA h stores + 3-slot +
//    L1-only inv, split flags cntA/cntB, weight L2 residency pattern.
// ---------------------------------------------------------------------------

typedef __bf16 bf16x8 __attribute__((ext_vector_type(8)));
typedef float  f32x4  __attribute__((ext_vector_type(4)));

#define HSZ   (512 * 1024)  // one h buffer: 512 rows x 1024 cols (bf16)

__device__ __forceinline__ float sigm_f(float x) {
    x = fminf(30.f, fmaxf(-30.f, x));
    return 1.0f / (1.0f + __expf(-x));
}
__device__ __forceinline__ float tanh_f(float x) {
    x = fminf(30.f, fmaxf(-30.f, x));
    float e = __expf(-2.0f * x);
    return (1.0f - e) / (1.0f + e);
}

// n' = (j/16)*64 + g*16 + (j%16)  ->  original gate-major row g*1024 + j
__device__ __forceinline__ int perm_row(int np) {
    int g = (np >> 4) & 3;
    int j = ((np >> 6) << 4) | (np & 15);
    return g * 1024 + j;
}

// ---- relaxed-only flag ops (NO acquire/release -> no L2 inv/wb) ------------
__device__ __forceinline__ void spin_ge(const int* p, int target) {
    while (__hip_atomic_load(p, __ATOMIC_RELAXED, __HIP_MEMORY_SCOPE_AGENT) < target)
        __builtin_amdgcn_s_sleep(1);
}
__device__ __forceinline__ void signal_inc(int* p) {
    __hip_atomic_fetch_add(p, 1, __ATOMIC_RELAXED, __HIP_MEMORY_SCOPE_AGENT);
}
// L1-only invalidate (CU scope). Leaves L2/MALL intact; compiler fence.
__device__ __forceinline__ void inv_l1() {
    asm volatile("buffer_inv" ::: "memory");
}
// EA-point coherent dword store: bypasses L2s -> visible chip-wide.
__device__ __forceinline__ void store_ea(unsigned* p, unsigned v) {
    __hip_atomic_store(p, v, __ATOMIC_RELAXED, __HIP_MEMORY_SCOPE_AGENT);
}

// ---------------- weight prep kernels (run every call) ----------------------

__global__ void prep_w0(const float* __restrict__ Wh0, __bf16* __restrict__ W0p) {
    int idx = blockIdx.x * 256 + threadIdx.x;
    int np = idx >> 8, k4 = (idx & 255) << 2;
    int r = perm_row(np);
    float4 v = *(const float4*)(Wh0 + r * 1024 + k4);
    __bf16* o = W0p + np * 1024 + k4;
    o[0] = (__bf16)v.x; o[1] = (__bf16)v.y; o[2] = (__bf16)v.z; o[3] = (__bf16)v.w;
}

__global__ void prep_w1(const float* __restrict__ Wi1, const float* __restrict__ Wh1,
                        __bf16* __restrict__ W1p) {
    int idx = blockIdx.x * 256 + threadIdx.x;
    int np = idx >> 9, k4 = (idx & 511) << 2;
    int r = perm_row(np);
    const float* s = (k4 < 1024) ? (Wi1 + r * 1024 + k4) : (Wh1 + r * 1024 + (k4 - 1024));
    float4 v = *(const float4*)s;
    __bf16* o = W1p + np * 2048 + k4;
    o[0] = (__bf16)v.x; o[1] = (__bf16)v.y; o[2] = (__bf16)v.z; o[3] = (__bf16)v.w;
}

__global__ void prep_wfc(const float* __restrict__ Wfc, __bf16* __restrict__ Wfcp) {
    int idx = blockIdx.x * 256 + threadIdx.x;
    int n = idx >> 8, k4 = (idx & 255) << 2;
    __bf16* o = Wfcp + n * 1024 + k4;
    if (n < 672) {
        float4 v = *(const float4*)(Wfc + n * 1024 + k4);
        o[0] = (__bf16)v.x; o[1] = (__bf16)v.y; o[2] = (__bf16)v.z; o[3] = (__bf16)v.w;
    } else {
        o[0] = (__bf16)0.f; o[1] = (__bf16)0.f; o[2] = (__bf16)0.f; o[3] = (__bf16)0.f;
    }
}

__global__ void prep_small(const float* __restrict__ Wi0, const float* __restrict__ b0,
                           const float* __restrict__ b1,
                           float* __restrict__ Wi0p, float* __restrict__ b1p) {
    int np = blockIdx.x * 256 + threadIdx.x;
    int r = perm_row(np);
    float* o = Wi0p + np * 8;
    #pragma unroll
    for (int q = 0; q < 7; ++q) o[q] = Wi0[r * 7 + q];
    o[7] = b0[r];
    b1p[np] = b1[r];
}

// ---------------- fused pipelined K=1024 sub-loop (512 threads/half) --------
// Tile 64x128, 8 waves in 4(m)x2(n), wave tile 16x64, BK=64, LDS dbuf,
// 1 barrier/iter, global loads 2 iters ahead. D0 -> acc0 (W0), D1 -> acc1.
// 17 barriers per call for EVERY <D0,D1> instantiation (structure is
// flag-independent) -- required for the v20 concurrent-halves scheme.
// LDS layout: 128B rows, phys = row*128 + ((chunk ^ (row&7))<<4).

template <bool D0, bool D1>
__device__ __forceinline__ void floop(const __bf16* __restrict__ abase,
                                      const __bf16* __restrict__ w0row,
                                      const __bf16* __restrict__ w1row,
                                      int tid,
                                      char* AldsB, char* B0ldsB, char* B1ldsB,
                                      f32x4 (&acc0)[4], f32x4 (&acc1)[4]) {
    const int a_r = tid >> 3;             // 0..63
    const int a_c = (tid & 7) << 3;       // 0..56 step 8 (16 B)
    const int b_r = tid >> 2;             // 0..127
    const int b_c = (tid & 3) << 4;       // 0,16,32,48 (2 x 16 B each)
    const int l  = tid & 63, w = tid >> 6;
    const int wm = w & 3,   wn = w >> 2;
    const int lj = l & 15,  lq = l >> 4;
    const int r7 = lj & 7;

    const __bf16* arw = abase + a_r * 1024 + a_c;

    // swizzled LDS byte offsets (writes)
    const int awr  = a_r * 128 + (((tid & 7) ^ (a_r & 7)) << 4);
    const int bwr0 = b_r * 128 + (((((tid & 3) << 1) | 0) ^ (b_r & 7)) << 4);
    const int bwr1 = b_r * 128 + (((((tid & 3) << 1) | 1) ^ (b_r & 7)) << 4);
    // swizzled chunk offsets (reads), chunk = (s<<2)|lq
    const int rc0 = ((lq     ) ^ r7) << 4;   // s = 0
    const int rc1 = ((lq | 4 ) ^ r7) << 4;   // s = 1

    uint4 ra, rb00, rb01, rb10, rb11;
    auto ld = [&](int k0) {
        ra = *(const uint4*)(arw + k0);
        if (D0) {
            const __bf16* p = w0row + k0;
            rb00 = *(const uint4*)(p);
            rb01 = *(const uint4*)(p + 8);
        }
        if (D1) {
            const __bf16* p = w1row + k0;
            rb10 = *(const uint4*)(p);
            rb11 = *(const uint4*)(p + 8);
        }
    };
    auto wr = [&](int buf) {
        *(uint4*)(AldsB + buf * 8192 + awr) = ra;
        if (D0) {
            char* Bl = B0ldsB + buf * 16384;
            *(uint4*)(Bl + bwr0) = rb00;
            *(uint4*)(Bl + bwr1) = rb01;
        }
        if (D1) {
            char* Bl = B1ldsB + buf * 16384;
            *(uint4*)(Bl + bwr0) = rb10;
            *(uint4*)(Bl + bwr1) = rb11;
        }
    };

    ld(0);
    wr(0);
    ld(64);
    __syncthreads();

    const char* Ap  = AldsB  + (wm * 16 + lj) * 128;
    const char* B0p = B0ldsB + (wn * 64 + lj) * 128;
    const char* B1p = B1ldsB + (wn * 64 + lj) * 128;

    for (int it = 0; it < 16; ++it) {
        const int bo = it & 1;
        const char* Ab  = Ap  + bo * 8192;
        const char* B0b = B0p + bo * 16384;
        const char* B1b = B1p + bo * 16384;
        #pragma unroll
        for (int s = 0; s < 2; ++s) {
            const int rc = s ? rc1 : rc0;
            bf16x8 af = *(const bf16x8*)(Ab + rc);
            #pragma unroll
            for (int ni = 0; ni < 4; ++ni) {
                if (D0) {
                    bf16x8 b0 = *(const bf16x8*)(B0b + ni * 2048 + rc);
                    acc0[ni] = __builtin_amdgcn_mfma_f32_16x16x32_bf16(af, b0, acc0[ni], 0, 0, 0);
                }
                if (D1) {
                    bf16x8 b1 = *(const bf16x8*)(B1b + ni * 2048 + rc);
                    acc1[ni] = __builtin_amdgcn_mfma_f32_16x16x32_bf16(af, b1, acc1[ni], 0, 0, 0);
                }
            }
        }
        if (it + 1 < 16) wr((it + 1) & 1);       // data loaded 1 iter ago
        if (it + 2 < 16) ld((it + 2) * 64);      // 2-iter prefetch distance
        __syncthreads();
    }
}

// ---------------- persistent fused LSTM kernel ------------------------------
// 256 blocks, 1/CU, 1024 threads (16 waves). xcd owns gate-col slice
// [512x,512x+512); slot -> mt (0..7) x nb (0..3). Round r (concurrent):
//   half0: L0(r) + Wi1-half of L1(r-1) on h_a(r-1)   [floop<D0,D1>]
//   half1: Wh1-half of L1(r-1) on h_b(r-2)           [floop<false,D1>]
// acc1 merge via retired B0lds; epilogues on half0. cntA/cntB as v19.

__global__ __launch_bounds__(1024)
void lstm_persist(const float* __restrict__ x,
                  const __bf16* __restrict__ W0p, const __bf16* __restrict__ W1p,
                  const __bf16* __restrict__ Wfcp,
                  const float* __restrict__ Wi0p, const float* __restrict__ b1p,
                  const float* __restrict__ bfc,
                  __bf16* __restrict__ bufA, __bf16* __restrict__ bufB,
                  char* __restrict__ flagpage, float* __restrict__ out) {
    __shared__ __attribute__((aligned(16))) char Alds[2 * 8192];      // 16 KB
    __shared__ __attribute__((aligned(16))) char B0lds[2 * 16384];    // 32 KB
    __shared__ __attribute__((aligned(16))) char B1lds[2 * 16384];    // 32 KB
    __shared__ __attribute__((aligned(16))) char A2lds[2 * 8192];     // 16 KB
    __shared__ __attribute__((aligned(16))) char B1bls[2 * 16384];    // 32 KB
    __shared__ float Aux1[128];
    __shared__ float Xlds[64 * 9];
    __shared__ float Wxlds[128 * 9];
    __shared__ int role[2];

    const int tid  = threadIdx.x;
    const int half = tid >> 9;        // 0: L0+L1a, 1: L1b
    const int t5   = tid & 511;

    // ---- claim XCD-local role ----
    if (tid == 0) {
        int xcd = __builtin_amdgcn_s_getreg(63508) & 7;   // HW_REG_XCC_ID
        int* xcnt = (int*)(flagpage + 1024) + xcd;
        int slot = __hip_atomic_fetch_add(xcnt, 1, __ATOMIC_RELAXED,
                                          __HIP_MEMORY_SCOPE_AGENT);
        role[0] = xcd; role[1] = slot;
    }
    __syncthreads();
    const int xcd = role[0];
    const int sl  = role[1];          // 0..31
    const int mt = sl >> 2, nb = sl & 3;
    const int m0 = mt * 64;
    const int n0 = xcd * 512 + nb * 128;
    int* cntA = (int*)(flagpage + (size_t)mt * 64);          // offsets 0..448
    int* cntB = (int*)(flagpage + 512 + (size_t)mt * 64);    // offsets 512..960

    // one-time epilogue constants (half0 threads only by construction)
    if (tid < 128) {
        Aux1[tid] = b1p[n0 + tid];
    } else if (tid < 256) {
        int nl = tid - 128;
        const float* sp = Wi0p + (n0 + nl) * 8;
        float* d = Wxlds + nl * 9;
        #pragma unroll
        for (int q = 0; q < 8; ++q) d[q] = sp[q];
    }

    const int b_r = t5 >> 2;
    const int b_c = (t5 & 3) << 4;
    const int l  = t5 & 63, w = t5 >> 6;
    const int wm = w & 3,   wn = w >> 2;
    const int lj = l & 15,  lq = l >> 4;
    const int jc = (n0 >> 2) + wn * 16 + lj;   // h column in [0,1024)

    const __bf16* w0row = W0p + (size_t)(n0 + b_r) * 1024 + b_c;
    const __bf16* w1row = W1p + (size_t)(n0 + b_r) * 2048 + b_c;

    float c0[4], c1[4];
    #pragma unroll
    for (int r = 0; r < 4; ++r) { c0[r] = 0.f; c1[r] = 0.f; }

    f32x4 acc0[4], acc1[4];

    for (int r = 0; r <= 128; ++r) {
        const bool do0 = (r < 128), do1 = (r > 0);
        const __bf16* haPrev = bufA + (size_t)(r % 3) * HSZ;        // h_a(r-1)
        __bf16*       haOut  = bufA + (size_t)((r + 1) % 3) * HSZ;  // h_a(r)
        const __bf16* hbPrev = bufB + (size_t)((r + 2) % 3) * HSZ;  // h_b(r-2)
        __bf16*       hbOut  = bufB + (size_t)(r % 3) * HSZ;        // h_b(r-1)

        // round start: need h_a(r-1) [cntA>=32r] and h_b(r-2) [cntB>=32r]
        if (tid == 0) { spin_ge(cntA, 32 * r); spin_ge(cntB, 32 * r); }
        __syncthreads();
        inv_l1();

        // stage x_r (read-only input)
        if (do0 && tid < 64) {
            const float* xr = x + (m0 + tid) * 896 + r * 7;
            float* d = Xlds + tid * 9;
            #pragma unroll
            for (int q = 0; q < 7; ++q) d[q] = xr[q];
            d[7] = 1.0f;
        }

        #pragma unroll
        for (int j = 0; j < 4; ++j) {
            acc0[j] = (f32x4){0.f, 0.f, 0.f, 0.f};
            acc1[j] = (f32x4){0.f, 0.f, 0.f, 0.f};
        }

        // ---- concurrent floops: 17 barriers in each path ----
        if (half == 0) {
            const __bf16* abase = haPrev + m0 * 1024;
            if (do0 && do1)
                floop<true, true >(abase, w0row, w1row, t5, Alds, B0lds, B1lds, acc0, acc1);
            else if (do0)
                floop<true, false>(abase, w0row, w1row, t5, Alds, B0lds, B1lds, acc0, acc1);
            else   // r == 128: Wi1-half on h_a(127)
                floop<false, true>(abase, w0row, w1row, t5, Alds, B0lds, B1lds, acc0, acc1);
        } else {
            const __bf16* abase2 = hbPrev + m0 * 1024;
            if (do1)
                floop<false, true >(abase2, w0row, w1row + 1024, t5, A2lds, B0lds, B1bls, acc0, acc1);
            else   // r == 0: barrier-matching no-op pass
                floop<false, false>(abase2, w0row, w1row, t5, A2lds, B0lds, B1bls, acc0, acc1);
        }

        // half1 exports its acc1 partial through retired B0lds (no reader
        // of B0lds after the final common barrier of the floops)
        if (half == 1 && do1) {
            #pragma unroll
            for (int j = 0; j < 4; ++j)
                *(f32x4*)(B0lds + t5 * 64 + j * 16) = acc1[j];
        }

        if (half == 0 && do0) {   // L0 epilogue: cell update + EA store h_a(r)
            #pragma unroll
            for (int rr = 0; rr < 4; ++rr) {
                int ml = wm * 16 + lq * 4 + rr;
                int m  = m0 + ml;
                float pre[4];
                #pragma unroll
                for (int g = 0; g < 4; ++g) pre[g] = acc0[g][rr];
                const float* xr = Xlds + ml * 9;
                #pragma unroll
                for (int g = 0; g < 4; ++g) {
                    const float* wx = Wxlds + (wn * 64 + g * 16 + lj) * 9;
                    float sv = 0.f;
                    #pragma unroll
                    for (int q = 0; q < 8; ++q) sv += xr[q] * wx[q];
                    pre[g] += sv;
                }
                float ig = sigm_f(pre[0]);
                float fg = sigm_f(pre[1]);
                float gv = tanh_f(pre[2]);
                float og = sigm_f(pre[3]);
                float cn = fg * c0[rr] + ig * gv;
                c0[rr] = cn;
                float hv = og * tanh_f(cn);
                unsigned u32 = __builtin_bit_cast(unsigned, hv);
                unsigned hu = (u32 + 0x7fffu + ((u32 >> 16) & 1u)) >> 16;
                int pv = __shfl_xor((int)hu, 1, 64);
                if ((lj & 1) == 0)
                    store_ea((unsigned*)(haOut + (size_t)m * 1024 + jc),
                             hu | ((unsigned)pv << 16));
            }
        }
        __syncthreads();                 // acc1 export visible + h_a drained
        if (tid == 0) signal_inc(cntA);

        if (half == 0 && do1) {   // merge + L1 epilogue + EA store h_b(r-1)
            #pragma unroll
            for (int j = 0; j < 4; ++j) {
                f32x4 p = *(const f32x4*)(B0lds + t5 * 64 + j * 16);
                acc1[j][0] += p[0]; acc1[j][1] += p[1];
                acc1[j][2] += p[2]; acc1[j][3] += p[3];
            }
            #pragma unroll
            for (int rr = 0; rr < 4; ++rr) {
                int m = m0 + wm * 16 + lq * 4 + rr;
                float pre[4];
                #pragma unroll
                for (int g = 0; g < 4; ++g)
                    pre[g] = acc1[g][rr] + Aux1[wn * 64 + g * 16 + lj];
                float ig = sigm_f(pre[0]);
                float fg = sigm_f(pre[1]);
                float gv = tanh_f(pre[2]);
                float og = sigm_f(pre[3]);
                float cn = fg * c1[rr] + ig * gv;
                c1[rr] = cn;
                float hv = og * tanh_f(cn);
                unsigned u32 = __builtin_bit_cast(unsigned, hv);
                unsigned hu = (u32 + 0x7fffu + ((u32 >> 16) & 1u)) >> 16;
                int pv = __shfl_xor((int)hu, 1, 64);
                if ((lj & 1) == 0)
                    store_ea((unsigned*)(hbOut + (size_t)m * 1024 + jc),
                             hu | ((unsigned)pv << 16));
            }
        }
        __syncthreads();                 // h_b stores drained
        if (tid == 0) signal_inc(cntB);
    }

    // ---- final FC: pred = h_b(127) @ Wfc^T + bfc  (nb==0, xcd<6) -----------
    if (nb == 0 && xcd < 6) {
        const int n0fc = xcd * 128;
        if (tid == 0) spin_ge(cntB, 32 * 129);
        __syncthreads();
        inv_l1();
        if (tid < 128) {
            int n = n0fc + tid;
            Aux1[tid] = (n < 672) ? bfc[n] : 0.f;
        }
        #pragma unroll
        for (int j = 0; j < 4; ++j)
            acc0[j] = (f32x4){0.f, 0.f, 0.f, 0.f};
        // h_b(127) written in round 128 into bufB slot 128%3 = 2
        if (half == 0)
            floop<true, false>(bufB + (size_t)2 * HSZ + m0 * 1024,
                               Wfcp + (size_t)(n0fc + b_r) * 1024 + b_c, nullptr,
                               t5, Alds, B0lds, B1lds, acc0, acc1);
        else   // barrier-matching no-op pass
            floop<false, false>(bufB + (size_t)2 * HSZ + m0 * 1024,
                                w0row, w1row, t5, A2lds, B0lds, B1bls, acc0, acc1);
        if (half == 0) {
            #pragma unroll
            for (int rr = 0; rr < 4; ++rr) {
                int m = m0 + wm * 16 + lq * 4 + rr;
                #pragma unroll
                for (int ni = 0; ni < 4; ++ni) {
                    int n = n0fc + wn * 64 + ni * 16 + lj;
                    if (n < 672)
                        out[m * 672 + n] = acc0[ni][rr] + Aux1[wn * 64 + ni * 16 + lj];
                }
            }
        }
    }
}

// ---------------- workspace layout (bytes) ----------------------------------
#define O_W0P   0u            // 4096*1024*2  = 8388608
#define O_W1P   8388608u      // 4096*2048*2  = 16777216
#define O_WFCP  25165824u     // 768*1024*2   = 1572864
#define O_WI0P  26738688u     // 4096*8*4     = 131072
#define O_B1P   26869760u     // 4096*4       = 16384
#define O_FLG   26886144u     // 2048: cntA@mt*64, cntB@512+mt*64, xcnt@1024
#define O_BA    26888192u     // bufA[3] = 3*1048576  (slot0 zeroed = h_a(-1))
#define O_BB    30033920u     // bufB[3] = 3*1048576  (slot0 zeroed = h_b(-1))
#define WS_NEED 33179648u

extern "C" void kernel_launch(void* const* d_in, const int* in_sizes, int n_in,
                              void* d_out, int out_size, void* d_ws, size_t ws_size,
                              hipStream_t stream) {
    const float* x   = (const float*)d_in[0];
    const float* Wi0 = (const float*)d_in[1];
    const float* Wh0 = (const float*)d_in[2];
    const float* b0  = (const float*)d_in[3];
    const float* Wi1 = (const float*)d_in[4];
    const float* Wh1 = (const float*)d_in[5];
    const float* b1  = (const float*)d_in[6];
    const float* Wfc = (const float*)d_in[7];
    const float* bfc = (const float*)d_in[8];
    float* out = (float*)d_out;
    char*  ws  = (char*)d_ws;
    if (ws_size < WS_NEED) return;

    __bf16* W0p  = (__bf16*)(ws + O_W0P);
    __bf16* W1p  = (__bf16*)(ws + O_W1P);
    __bf16* Wfcp = (__bf16*)(ws + O_WFCP);
    float*  Wi0p = (float*)(ws + O_WI0P);
    float*  b1p  = (float*)(ws + O_B1P);
    char*   flg  = (char*)(ws + O_FLG);
    __bf16* bufA = (__bf16*)(ws + O_BA);
    __bf16* bufB = (__bf16*)(ws + O_BB);

    // zero flags + bufA slot0 (contiguous), and bufB slot0
    hipMemsetAsync(ws + O_FLG, 0, 2048u + 1048576u, stream);
    hipMemsetAsync(ws + O_BB, 0, 1048576u, stream);

    prep_w0   <<<4096, 256, 0, stream>>>(Wh0, W0p);
    prep_w1   <<<8192, 256, 0, stream>>>(Wi1, Wh1, W1p);
    prep_wfc  <<<768,  256, 0, stream>>>(Wfc, Wfcp);
    prep_small<<<16,   256, 0, stream>>>(Wi0, b0, b1, Wi0p, b1p);

    lstm_persist<<<256, 1024, 0, stream>>>(x, W0p, W1p, Wfcp, Wi0p, b1p, bfc,
                                           bufA, bufB, flg, out);
}

// Round 10
// 2958.564 us; speedup vs baseline: 1.0136x; 1.0136x over previous
//
#include <hip/hip_runtime.h>
#include <hip/hip_bf16.h>

// ---------------------------------------------------------------------------
// LSTM_66675072303478: 2-layer LSTM (B=512,S=128,E=7,H=1024) + FC(1024->672)
//
// v21 = v19 (2828us best) with floop1+floop2 FUSED into one 16-iter loop:
// per iteration each wave advances TWO independent GEMM chains (GEMM1: A=h_a
// with B0/B1, 16 MFMA; GEMM2: A2=h_b with B1b, 8 MFMA) on disjoint LDS
// buffers and accumulators.
//  - v20 post-mortem: TLP halves failed because the per-iter barrier parks
//    the lighter half (8 vs 16 MFMA/segment) before the heavy half's stall
//    windows -> no overlap; MfmaUtil stuck at 23% despite 2x occupancy.
//    In-wave fusion puts both chains in ONE instruction stream between the
//    same barriers: compiler interleaves chain2 MFMAs under chain1's lgkm
//    waits. Equal per-iter work for all 8 waves -> no skew. Barriers/round
//    34 -> 17. Effective 583 TF sits at the known 2-phase GEMM structural
//    ceiling (m230/m233); this attacks the stage->wait->barrier->compute
//    serialization without the full 8-phase rewrite.
//  - Global/LDS/MFMA totals per round byte-identical to v19; only
//    interleaving changes (weight streams still linear -> L2 residency kept).
//  - Protocol = v20's verified variant: both waits (cntA,cntB >= 32r) at
//    round start, one inv_l1; then fused loop; epilogue A -> drain -> incA;
//    epilogue B -> drain -> incB (v19 split-flag publish order kept).
//  - All else proven & verbatim: v15 staging/index math, XOR swizzle
//    phys=row*128+((chunk^(row&7))<<4) (0 conflicts), gate-interleaved
//    epilogues, EA h stores + 3-slot rotation + L1-only inv, per-mt flags.
// ---------------------------------------------------------------------------

typedef __bf16 bf16x8 __attribute__((ext_vector_type(8)));
typedef float  f32x4  __attribute__((ext_vector_type(4)));

#define HSZ   (512 * 1024)  // one h buffer: 512 rows x 1024 cols (bf16)

__device__ __forceinline__ float sigm_f(float x) {
    x = fminf(30.f, fmaxf(-30.f, x));
    return 1.0f / (1.0f + __expf(-x));
}
__device__ __forceinline__ float tanh_f(float x) {
    x = fminf(30.f, fmaxf(-30.f, x));
    float e = __expf(-2.0f * x);
    return (1.0f - e) / (1.0f + e);
}

// n' = (j/16)*64 + g*16 + (j%16)  ->  original gate-major row g*1024 + j
__device__ __forceinline__ int perm_row(int np) {
    int g = (np >> 4) & 3;
    int j = ((np >> 6) << 4) | (np & 15);
    return g * 1024 + j;
}

// ---- relaxed-only flag ops (NO acquire/release -> no L2 inv/wb) ------------
__device__ __forceinline__ void spin_ge(const int* p, int target) {
    while (__hip_atomic_load(p, __ATOMIC_RELAXED, __HIP_MEMORY_SCOPE_AGENT) < target)
        __builtin_amdgcn_s_sleep(1);
}
__device__ __forceinline__ void signal_inc(int* p) {
    __hip_atomic_fetch_add(p, 1, __ATOMIC_RELAXED, __HIP_MEMORY_SCOPE_AGENT);
}
// L1-only invalidate (CU scope). Leaves L2/MALL intact; compiler fence.
__device__ __forceinline__ void inv_l1() {
    asm volatile("buffer_inv" ::: "memory");
}
// EA-point coherent dword store: bypasses L2s -> visible chip-wide.
__device__ __forceinline__ void store_ea(unsigned* p, unsigned v) {
    __hip_atomic_store(p, v, __ATOMIC_RELAXED, __HIP_MEMORY_SCOPE_AGENT);
}

// ---------------- weight prep kernels (run every call) ----------------------

__global__ void prep_w0(const float* __restrict__ Wh0, __bf16* __restrict__ W0p) {
    int idx = blockIdx.x * 256 + threadIdx.x;
    int np = idx >> 8, k4 = (idx & 255) << 2;
    int r = perm_row(np);
    float4 v = *(const float4*)(Wh0 + r * 1024 + k4);
    __bf16* o = W0p + np * 1024 + k4;
    o[0] = (__bf16)v.x; o[1] = (__bf16)v.y; o[2] = (__bf16)v.z; o[3] = (__bf16)v.w;
}

__global__ void prep_w1(const float* __restrict__ Wi1, const float* __restrict__ Wh1,
                        __bf16* __restrict__ W1p) {
    int idx = blockIdx.x * 256 + threadIdx.x;
    int np = idx >> 9, k4 = (idx & 511) << 2;
    int r = perm_row(np);
    const float* s = (k4 < 1024) ? (Wi1 + r * 1024 + k4) : (Wh1 + r * 1024 + (k4 - 1024));
    float4 v = *(const float4*)s;
    __bf16* o = W1p + np * 2048 + k4;
    o[0] = (__bf16)v.x; o[1] = (__bf16)v.y; o[2] = (__bf16)v.z; o[3] = (__bf16)v.w;
}

__global__ void prep_wfc(const float* __restrict__ Wfc, __bf16* __restrict__ Wfcp) {
    int idx = blockIdx.x * 256 + threadIdx.x;
    int n = idx >> 8, k4 = (idx & 255) << 2;
    __bf16* o = Wfcp + n * 1024 + k4;
    if (n < 672) {
        float4 v = *(const float4*)(Wfc + n * 1024 + k4);
        o[0] = (__bf16)v.x; o[1] = (__bf16)v.y; o[2] = (__bf16)v.z; o[3] = (__bf16)v.w;
    } else {
        o[0] = (__bf16)0.f; o[1] = (__bf16)0.f; o[2] = (__bf16)0.f; o[3] = (__bf16)0.f;
    }
}

__global__ void prep_small(const float* __restrict__ Wi0, const float* __restrict__ b0,
                           const float* __restrict__ b1,
                           float* __restrict__ Wi0p, float* __restrict__ b1p) {
    int np = blockIdx.x * 256 + threadIdx.x;
    int r = perm_row(np);
    float* o = Wi0p + np * 8;
    #pragma unroll
    for (int q = 0; q < 7; ++q) o[q] = Wi0[r * 7 + q];
    o[7] = b0[r];
    b1p[np] = b1[r];
}

// ---------------- fused dual-GEMM K=1024 loop (512 threads) -----------------
// GEMM1: 64x128 tile, A=h_a, B0(W0)+B1(Wi1) -> acc0, acc1.  GEMM2: A2=h_b,
// B1b(Wh1) -> acc1.  8 waves 4(m)x2(n), wave tile 16x64, BK=64, LDS dbuf,
// 1 barrier/iter (17 total), global loads 2 iters ahead. Two independent
// chains per wave -> ILP. LDS: 128B rows, phys = row*128+((chunk^(row&7))<<4).

template <bool D0, bool D1, bool D2>
__device__ __forceinline__ void floopf(const __bf16* __restrict__ abase,
                                       const __bf16* __restrict__ abase2,
                                       const __bf16* __restrict__ w0row,
                                       const __bf16* __restrict__ w1row,
                                       const __bf16* __restrict__ w1rowB,
                                       int tid,
                                       char* AldsB, char* B0ldsB, char* B1ldsB,
                                       char* A2ldsB, char* B1bldsB,
                                       f32x4 (&acc0)[4], f32x4 (&acc1)[4]) {
    const int a_r = tid >> 3;             // 0..63
    const int a_c = (tid & 7) << 3;       // 0..56 step 8 (16 B)
    const int b_r = tid >> 2;             // 0..127
    const int b_c = (tid & 3) << 4;       // 0,16,32,48 (2 x 16 B each)
    const int l  = tid & 63, w = tid >> 6;
    const int wm = w & 3,   wn = w >> 2;
    const int lj = l & 15,  lq = l >> 4;
    const int r7 = lj & 7;

    const __bf16* arw  = abase  + a_r * 1024 + a_c;
    const __bf16* arw2 = abase2 + a_r * 1024 + a_c;

    // swizzled LDS byte offsets (writes)
    const int awr  = a_r * 128 + (((tid & 7) ^ (a_r & 7)) << 4);
    const int bwr0 = b_r * 128 + (((((tid & 3) << 1) | 0) ^ (b_r & 7)) << 4);
    const int bwr1 = b_r * 128 + (((((tid & 3) << 1) | 1) ^ (b_r & 7)) << 4);
    // swizzled chunk offsets (reads), chunk = (s<<2)|lq
    const int rc0 = ((lq     ) ^ r7) << 4;   // s = 0
    const int rc1 = ((lq | 4 ) ^ r7) << 4;   // s = 1

    uint4 ra, rb00, rb01, rb10, rb11;        // chain 1 staging
    uint4 ra2, rc10, rc11;                   // chain 2 staging
    auto ld = [&](int k0) {
        ra = *(const uint4*)(arw + k0);
        if (D0) {
            const __bf16* p = w0row + k0;
            rb00 = *(const uint4*)(p);
            rb01 = *(const uint4*)(p + 8);
        }
        if (D1) {
            const __bf16* p = w1row + k0;
            rb10 = *(const uint4*)(p);
            rb11 = *(const uint4*)(p + 8);
        }
        if (D2) {
            ra2 = *(const uint4*)(arw2 + k0);
            const __bf16* p = w1rowB + k0;
            rc10 = *(const uint4*)(p);
            rc11 = *(const uint4*)(p + 8);
        }
    };
    auto wr = [&](int buf) {
        *(uint4*)(AldsB + buf * 8192 + awr) = ra;
        if (D0) {
            char* Bl = B0ldsB + buf * 16384;
            *(uint4*)(Bl + bwr0) = rb00;
            *(uint4*)(Bl + bwr1) = rb01;
        }
        if (D1) {
            char* Bl = B1ldsB + buf * 16384;
            *(uint4*)(Bl + bwr0) = rb10;
            *(uint4*)(Bl + bwr1) = rb11;
        }
        if (D2) {
            *(uint4*)(A2ldsB + buf * 8192 + awr) = ra2;
            char* Bl = B1bldsB + buf * 16384;
            *(uint4*)(Bl + bwr0) = rc10;
            *(uint4*)(Bl + bwr1) = rc11;
        }
    };

    ld(0);
    wr(0);
    ld(64);
    __syncthreads();

    const char* Ap   = AldsB   + (wm * 16 + lj) * 128;
    const char* A2p  = A2ldsB  + (wm * 16 + lj) * 128;
    const char* B0p  = B0ldsB  + (wn * 64 + lj) * 128;
    const char* B1p  = B1ldsB  + (wn * 64 + lj) * 128;
    const char* B1bp = B1bldsB + (wn * 64 + lj) * 128;

    for (int it = 0; it < 16; ++it) {
        const int bo = it & 1;
        const char* Ab   = Ap   + bo * 8192;
        const char* A2b  = A2p  + bo * 8192;
        const char* B0b  = B0p  + bo * 16384;
        const char* B1b  = B1p  + bo * 16384;
        const char* B1bb = B1bp + bo * 16384;
        #pragma unroll
        for (int s = 0; s < 2; ++s) {
            const int rc = s ? rc1 : rc0;
            bf16x8 af = *(const bf16x8*)(Ab + rc);
            bf16x8 af2;
            if (D2) af2 = *(const bf16x8*)(A2b + rc);
            #pragma unroll
            for (int ni = 0; ni < 4; ++ni) {
                if (D0) {
                    bf16x8 b0 = *(const bf16x8*)(B0b + ni * 2048 + rc);
                    acc0[ni] = __builtin_amdgcn_mfma_f32_16x16x32_bf16(af, b0, acc0[ni], 0, 0, 0);
                }
                if (D1) {
                    bf16x8 b1 = *(const bf16x8*)(B1b + ni * 2048 + rc);
                    acc1[ni] = __builtin_amdgcn_mfma_f32_16x16x32_bf16(af, b1, acc1[ni], 0, 0, 0);
                }
                if (D2) {
                    bf16x8 b2 = *(const bf16x8*)(B1bb + ni * 2048 + rc);
                    acc1[ni] = __builtin_amdgcn_mfma_f32_16x16x32_bf16(af2, b2, acc1[ni], 0, 0, 0);
                }
            }
        }
        if (it + 1 < 16) wr((it + 1) & 1);       // data loaded 1 iter ago
        if (it + 2 < 16) ld((it + 2) * 64);      // 2-iter prefetch distance
        __syncthreads();
    }
}

// ---------------- persistent fused LSTM kernel ------------------------------
// 256 blocks, 1/CU, 512 threads. xcd owns gate-col slice [512x,512x+512);
// slot -> mt (0..7) x nb (0..3). Round r: fused {L0(r) [r<128] + full L1(r-1)
// [r>0]}; waits cntA,cntB >= 32r at round start (v20-verified protocol);
// publish h_a (incA) before L1 epilogue, then h_b (incB).

__global__ __launch_bounds__(512)
void lstm_persist(const float* __restrict__ x,
                  const __bf16* __restrict__ W0p, const __bf16* __restrict__ W1p,
                  const __bf16* __restrict__ Wfcp,
                  const float* __restrict__ Wi0p, const float* __restrict__ b1p,
                  const float* __restrict__ bfc,
                  __bf16* __restrict__ bufA, __bf16* __restrict__ bufB,
                  char* __restrict__ flagpage, float* __restrict__ out) {
    __shared__ __attribute__((aligned(16))) char Alds[2 * 8192];      // 16 KB
    __shared__ __attribute__((aligned(16))) char B0lds[2 * 16384];    // 32 KB
    __shared__ __attribute__((aligned(16))) char B1lds[2 * 16384];    // 32 KB
    __shared__ __attribute__((aligned(16))) char A2lds[2 * 8192];     // 16 KB
    __shared__ __attribute__((aligned(16))) char B1blds[2 * 16384];   // 32 KB
    __shared__ float Aux1[128];
    __shared__ float Xlds[64 * 9];
    __shared__ float Wxlds[128 * 9];
    __shared__ int role[2];

    const int tid = threadIdx.x;

    // ---- claim XCD-local role ----
    if (tid == 0) {
        int xcd = __builtin_amdgcn_s_getreg(63508) & 7;   // HW_REG_XCC_ID
        int* xcnt = (int*)(flagpage + 1024) + xcd;
        int slot = __hip_atomic_fetch_add(xcnt, 1, __ATOMIC_RELAXED,
                                          __HIP_MEMORY_SCOPE_AGENT);
        role[0] = xcd; role[1] = slot;
    }
    __syncthreads();
    const int xcd = role[0];
    const int sl  = role[1];          // 0..31
    const int mt = sl >> 2, nb = sl & 3;
    const int m0 = mt * 64;
    const int n0 = xcd * 512 + nb * 128;
    int* cntA = (int*)(flagpage + (size_t)mt * 64);          // offsets 0..448
    int* cntB = (int*)(flagpage + 512 + (size_t)mt * 64);    // offsets 512..960

    // one-time epilogue constants
    if (tid < 128) {
        Aux1[tid] = b1p[n0 + tid];
    } else if (tid < 256) {
        int nl = tid - 128;
        const float* sp = Wi0p + (n0 + nl) * 8;
        float* d = Wxlds + nl * 9;
        #pragma unroll
        for (int q = 0; q < 8; ++q) d[q] = sp[q];
    }

    const int b_r = tid >> 2;
    const int b_c = (tid & 3) << 4;
    const int l  = tid & 63, w = tid >> 6;
    const int wm = w & 3,   wn = w >> 2;
    const int lj = l & 15,  lq = l >> 4;
    const int jc = (n0 >> 2) + wn * 16 + lj;   // h column in [0,1024)

    const __bf16* w0row = W0p + (size_t)(n0 + b_r) * 1024 + b_c;
    const __bf16* w1row = W1p + (size_t)(n0 + b_r) * 2048 + b_c;

    float c0[4], c1[4];
    #pragma unroll
    for (int r = 0; r < 4; ++r) { c0[r] = 0.f; c1[r] = 0.f; }

    f32x4 acc0[4], acc1[4];

    for (int r = 0; r <= 128; ++r) {
        const bool do0 = (r < 128), do1 = (r > 0);
        const __bf16* haPrev = bufA + (size_t)(r % 3) * HSZ;        // h_a(r-1)
        __bf16*       haOut  = bufA + (size_t)((r + 1) % 3) * HSZ;  // h_a(r)
        const __bf16* hbPrev = bufB + (size_t)((r + 2) % 3) * HSZ;  // h_b(r-2)
        __bf16*       hbOut  = bufB + (size_t)(r % 3) * HSZ;        // h_b(r-1)

        // round start: need h_a(r-1) [cntA>=32r] and h_b(r-2) [cntB>=32r]
        if (tid == 0) { spin_ge(cntA, 32 * r); spin_ge(cntB, 32 * r); }
        __syncthreads();
        inv_l1();

        // stage x_r (read-only input)
        if (do0 && tid < 64) {
            const float* xr = x + (m0 + tid) * 896 + r * 7;
            float* d = Xlds + tid * 9;
            #pragma unroll
            for (int q = 0; q < 7; ++q) d[q] = xr[q];
            d[7] = 1.0f;
        }

        #pragma unroll
        for (int j = 0; j < 4; ++j) {
            acc0[j] = (f32x4){0.f, 0.f, 0.f, 0.f};
            acc1[j] = (f32x4){0.f, 0.f, 0.f, 0.f};
        }

        const __bf16* abase  = haPrev + m0 * 1024;
        const __bf16* abase2 = hbPrev + m0 * 1024;
        if (do0 && do1)
            floopf<true, true, true >(abase, abase2, w0row, w1row, w1row + 1024,
                                      tid, Alds, B0lds, B1lds, A2lds, B1blds, acc0, acc1);
        else if (do0)
            floopf<true, false, false>(abase, abase2, w0row, w1row, w1row + 1024,
                                       tid, Alds, B0lds, B1lds, A2lds, B1blds, acc0, acc1);
        else   // r == 128: full L1 on h_a(127), h_b(126)
            floopf<false, true, true>(abase, abase2, w0row, w1row, w1row + 1024,
                                      tid, Alds, B0lds, B1lds, A2lds, B1blds, acc0, acc1);

        if (do0) {   // L0 epilogue: cell update + EA store h_a(r)
            #pragma unroll
            for (int rr = 0; rr < 4; ++rr) {
                int ml = wm * 16 + lq * 4 + rr;
                int m  = m0 + ml;
                float pre[4];
                #pragma unroll
                for (int g = 0; g < 4; ++g) pre[g] = acc0[g][rr];
                const float* xr = Xlds + ml * 9;
                #pragma unroll
                for (int g = 0; g < 4; ++g) {
                    const float* wx = Wxlds + (wn * 64 + g * 16 + lj) * 9;
                    float sv = 0.f;
                    #pragma unroll
                    for (int q = 0; q < 8; ++q) sv += xr[q] * wx[q];
                    pre[g] += sv;
                }
                float ig = sigm_f(pre[0]);
                float fg = sigm_f(pre[1]);
                float gv = tanh_f(pre[2]);
                float og = sigm_f(pre[3]);
                float cn = fg * c0[rr] + ig * gv;
                c0[rr] = cn;
                float hv = og * tanh_f(cn);
                unsigned u32 = __builtin_bit_cast(unsigned, hv);
                unsigned hu = (u32 + 0x7fffu + ((u32 >> 16) & 1u)) >> 16;
                int pv = __shfl_xor((int)hu, 1, 64);
                if ((lj & 1) == 0)
                    store_ea((unsigned*)(haOut + (size_t)m * 1024 + jc),
                             hu | ((unsigned)pv << 16));
            }
        }
        __syncthreads();                 // vmcnt(0): h_a stores performed
        if (tid == 0) signal_inc(cntA);

        if (do1) {   // L1 epilogue: cell update + EA store h_b(r-1)
            #pragma unroll
            for (int rr = 0; rr < 4; ++rr) {
                int m = m0 + wm * 16 + lq * 4 + rr;
                float pre[4];
                #pragma unroll
                for (int g = 0; g < 4; ++g)
                    pre[g] = acc1[g][rr] + Aux1[wn * 64 + g * 16 + lj];
                float ig = sigm_f(pre[0]);
                float fg = sigm_f(pre[1]);
                float gv = tanh_f(pre[2]);
                float og = sigm_f(pre[3]);
                float cn = fg * c1[rr] + ig * gv;
                c1[rr] = cn;
                float hv = og * tanh_f(cn);
                unsigned u32 = __builtin_bit_cast(unsigned, hv);
                unsigned hu = (u32 + 0x7fffu + ((u32 >> 16) & 1u)) >> 16;
                int pv = __shfl_xor((int)hu, 1, 64);
                if ((lj & 1) == 0)
                    store_ea((unsigned*)(hbOut + (size_t)m * 1024 + jc),
                             hu | ((unsigned)pv << 16));
            }
        }
        __syncthreads();                 // vmcnt(0): h_b stores performed
        if (tid == 0) signal_inc(cntB);
    }

    // ---- final FC: pred = h_b(127) @ Wfc^T + bfc  (nb==0, xcd<6) -----------
    if (nb == 0 && xcd < 6) {
        const int n0fc = xcd * 128;
        if (tid == 0) spin_ge(cntB, 32 * 129);
        __syncthreads();
        inv_l1();
        if (tid < 128) {
            int n = n0fc + tid;
            Aux1[tid] = (n < 672) ? bfc[n] : 0.f;
        }
        #pragma unroll
        for (int j = 0; j < 4; ++j)
            acc0[j] = (f32x4){0.f, 0.f, 0.f, 0.f};
        // h_b(127) written in round 128 into bufB slot 128%3 = 2
        const __bf16* hfin = bufB + (size_t)2 * HSZ + m0 * 1024;
        floopf<true, false, false>(hfin, hfin,
                                   Wfcp + (size_t)(n0fc + b_r) * 1024 + b_c,
                                   w1row, w1row + 1024,
                                   tid, Alds, B0lds, B1lds, A2lds, B1blds, acc0, acc1);
        #pragma unroll
        for (int rr = 0; rr < 4; ++rr) {
            int m = m0 + wm * 16 + lq * 4 + rr;
            #pragma unroll
            for (int ni = 0; ni < 4; ++ni) {
                int n = n0fc + wn * 64 + ni * 16 + lj;
                if (n < 672)
                    out[m * 672 + n] = acc0[ni][rr] + Aux1[wn * 64 + ni * 16 + lj];
            }
        }
    }
}

// ---------------- workspace layout (bytes) ----------------------------------
#define O_W0P   0u            // 4096*1024*2  = 8388608
#define O_W1P   8388608u      // 4096*2048*2  = 16777216
#define O_WFCP  25165824u     // 768*1024*2   = 1572864
#define O_WI0P  26738688u     // 4096*8*4     = 131072
#define O_B1P   26869760u     // 4096*4       = 16384
#define O_FLG   26886144u     // 2048: cntA@mt*64, cntB@512+mt*64, xcnt@1024
#define O_BA    26888192u     // bufA[3] = 3*1048576  (slot0 zeroed = h_a(-1))
#define O_BB    30033920u     // bufB[3] = 3*1048576  (slot0 zeroed = h_b(-1))
#define WS_NEED 33179648u

extern "C" void kernel_launch(void* const* d_in, const int* in_sizes, int n_in,
                              void* d_out, int out_size, void* d_ws, size_t ws_size,
                              hipStream_t stream) {
    const float* x   = (const float*)d_in[0];
    const float* Wi0 = (const float*)d_in[1];
    const float* Wh0 = (const float*)d_in[2];
    const float* b0  = (const float*)d_in[3];
    const float* Wi1 = (const float*)d_in[4];
    const float* Wh1 = (const float*)d_in[5];
    const float* b1  = (const float*)d_in[6];
    const float* Wfc = (const float*)d_in[7];
    const float* bfc = (const float*)d_in[8];
    float* out = (float*)d_out;
    char*  ws  = (char*)d_ws;
    if (ws_size < WS_NEED) return;

    __bf16* W0p  = (__bf16*)(ws + O_W0P);
    __bf16* W1p  = (__bf16*)(ws + O_W1P);
    __bf16* Wfcp = (__bf16*)(ws + O_WFCP);
    float*  Wi0p = (float*)(ws + O_WI0P);
    float*  b1p  = (float*)(ws + O_B1P);
    char*   flg  = (char*)(ws + O_FLG);
    __bf16* bufA = (__bf16*)(ws + O_BA);
    __bf16* bufB = (__bf16*)(ws + O_BB);

    // zero flags + bufA slot0 (contiguous), and bufB slot0
    hipMemsetAsync(ws + O_FLG, 0, 2048u + 1048576u, stream);
    hipMemsetAsync(ws + O_BB, 0, 1048576u, stream);

    prep_w0   <<<4096, 256, 0, stream>>>(Wh0, W0p);
    prep_w1   <<<8192, 256, 0, stream>>>(Wi1, Wh1, W1p);
    prep_wfc  <<<768,  256, 0, stream>>>(Wfc, Wfcp);
    prep_small<<<16,   256, 0, stream>>>(Wi0, b0, b1, Wi0p, b1p);

    lstm_persist<<<256, 512, 0, stream>>>(x, W0p, W1p, Wfcp, Wi0p, b1p, bfc,
                                          bufA, bufB, flg, out);
}